// Round 15
// baseline (126.689 us; speedup 1.0000x reference)
//
#include <hip/hip_runtime.h>

constexpr int   BATCH = 2;
constexpr int   NPTS  = 524288;            // P = 2^19
constexpr int   BINS  = 2048;              // BATCH * 32 * 32 tiles
constexpr int   CAP   = 768;               // per-bin capacity (mean 512, +11 sigma)
constexpr float BETA  = 4.71238898038469f; // 1.5*pi
constexpr float PI_F  = 3.14159265358979f;

typedef float v2f __attribute__((ext_vector_type(2)));

// LDS pad-16: breaks power-of-2 strides (butterflies + digit-rev readout)
#define PIDX(i) ((i) + ((i) >> 4))

// ---------------- workspace layout ----------------
// g       : 16 MB @ 0
// gcnt    : 8 KB  @ 16 MB       (zeroed by block 0 of rows_and_bin)
// perm_xy : BINS*CAP v2f = 12.6 MB
// perm_id : BINS*CAP int =  6.3 MB
constexpr size_t G_BYTES  = (size_t)BATCH * 1024 * 1024 * sizeof(v2f);
constexpr size_t GCNT_OFF = G_BYTES;
constexpr size_t PXY_OFF  = G_BYTES + 8192;
constexpr size_t PID_OFF  = PXY_OFF + (size_t)BINS * CAP * sizeof(v2f);

// i0(x) for x >= 3.75 (Numerical Recipes asymptotic, rel err ~1e-7)
__device__ __forceinline__ float i0f_large(float x) {
    float t = 3.75f / x;
    float p =  0.00392377f;
    p = p * t + -0.01647633f;
    p = p * t +  0.02635537f;
    p = p * t + -0.02057706f;
    p = p * t +  0.00916281f;
    p = p * t + -0.00157565f;
    p = p * t +  0.00225319f;
    p = p * t +  0.01328592f;
    p = p * t +  0.39894228f;
    return __expf(x) * rsqrtf(x) * p;
}

__device__ __forceinline__ int tile_of(v2f xv, int b) {
    int c1 = ((int)floorf(xv.x * 1024.0f)) & 1023;
    int c2 = ((int)floorf(xv.y * 1024.0f)) & 1023;
    return (b << 10) + ((c1 >> 5) << 5) + (c2 >> 5);
}

// cmul via packed f32: t stores (c, s, -s, c); a*w = a.x*(c,s) + a.y*(-s,c)
__device__ __forceinline__ v2f cmul4(v2f a, float4 t) {
    v2f lo = {t.x, t.y}, hi = {t.z, t.w};
    return a.x * lo + a.y * hi;            // v_pk_mul + v_pk_fma
}
__device__ __forceinline__ v2f irot(v2f b) { return (v2f){-b.y, b.x}; }  // i*b
__device__ __forceinline__ v2f cmulv(v2f a, v2f b) {
    return (v2f){a.x * b.x - a.y * b.y, a.x * b.y + a.y * b.x};
}
__device__ __forceinline__ float4 tw4p(v2f w) {
    return make_float4(w.x, w.y, -w.y, w.x);
}

// Natural freq f -> storage position after radix-4 DIF (5 digit-reversed
// base-4 digits) = bit-reverse then swap bits within pairs. Involution.
__device__ __forceinline__ int digitrev4_10(int f) {
    unsigned r = __brev((unsigned)f) >> 22;
    return (int)(((r & 0x2AAu) >> 1) | ((r & 0x155u) << 1));
}

// Build stage-concatenated twiddles starting at stage (q0, sig0), nst stages.
// Per stage: [w1: j<q][w2: j<q][w3: j<q], w_u = e^{-2 pi i u j sig / 1024}.
__device__ __forceinline__ void build_tw_small(float4* T, int tid, int nthreads,
                                               int q0, int sig0, int nst) {
    int off = 0, q = q0, sig = sig0;
    for (int st = 0; st < nst; ++st) {
        for (int m = tid; m < 3 * q; m += nthreads) {
            int sec = m / q, j = m - sec * q;
            float ang = (-2.0f * PI_F / 1024.0f) * (float)((sec + 1) * j * sig);
            float sw, cw;
            __sincosf(ang, &sw, &cw);
            T[off + m] = make_float4(cw, sw, -sw, cw);
        }
        off += 3 * q; q >>= 2; sig <<= 2;
    }
}

// One radix-4 DIF butterfly at index bt for stage with quarter-stride q.
__device__ __forceinline__ void bfly4(v2f* s, const float4* T,
                                      int bt, int q, int off) {
    int j    = bt & (q - 1);
    int base = ((bt - j) << 2) + j;        // (bt/q)*4q + j
    int p0 = PIDX(base), p1 = PIDX(base + q);
    int p2 = PIDX(base + 2 * q), p3 = PIDX(base + 3 * q);
    v2f a0 = s[p0], a1 = s[p1], a2 = s[p2], a3 = s[p3];
    v2f t0 = a0 + a2, t1 = a0 - a2, t2 = a1 + a3, t3 = a1 - a3;
    v2f r3 = irot(t3);
    s[p0] = t0 + t2;
    s[p1] = cmul4(t1 - r3, T[off + j]);
    s[p2] = cmul4(t0 - t2, T[off + q + j]);
    s[p3] = cmul4(t1 + r3, T[off + 2 * q + j]);
}

// ---------------- fused: row FFTs (blocks 0..511, BOTH batches per block)
//                  + binning (blocks 512..767, 4096 pts each) ----------------
// Row blocks amortize twiddle-table build + window coefficients over the two
// batches' FFTs of the same row. Block 0 zeroes gcnt at t~0 (bin blocks do
// >=2us of loads + LDS histogram before touching gcnt).
__global__ __launch_bounds__(256) void rows_and_bin(const v2f* __restrict__ fh,
                                                    v2f* __restrict__ g,
                                                    const v2f* __restrict__ x,
                                                    int* __restrict__ gcnt,
                                                    v2f* __restrict__ pxy,
                                                    int* __restrict__ pid) {
    // fft path: s = 1088 v2f (8704 B), T = 255 float4 (4080 B) -> 12784 B
    __shared__ __align__(16) char smem[12784];
    int tid = threadIdx.x;

    if (blockIdx.x < 512) {
        if (blockIdx.x == 0) {
            #pragma unroll
            for (int i = 0; i < 8; ++i)
                atomicExch(&gcnt[tid * 8 + i], 0);
        }
        // ---- row FFT fused with deconvolution (radix-4), b = 0 and 1 ----
        v2f*    s = (v2f*)smem;                  // 1087 used
        float4* T = (float4*)(smem + 8704);      // 255: q=64 @0, 16 @192, 4 @240
        int blk = blockIdx.x;                    // 0..511
        int row = (blk < 256) ? blk : blk + 512; // {0..255, 768..1023}
        int a1  = (row + 256) & 1023;            // fh row index, 0..511

        build_tw_small(T, tid, 256, 64, 4, 4);

        float k1 = (float)(a1 - 256);
        float w1 = (2.0f * PI_F / 1024.0f) * k1;
        float c1 = i0f_large(4.0f * sqrtf(BETA * BETA - w1 * w1));

        float w2a = (2.0f * PI_F / 1024.0f) * (float)tid;
        float c2a = i0f_large(4.0f * sqrtf(BETA * BETA - w2a * w2a));
        float w2b = (2.0f * PI_F / 1024.0f) * (float)(tid - 256);
        float c2b = i0f_large(4.0f * sqrtf(BETA * BETA - w2b * w2b));
        float ia = 1.0f / (c1 * c2a);
        float ib = 1.0f / (c1 * c2b);

        // both batches' loads issue up front (double MLP)
        const v2f* fr0 = fh + ((long)a1 << 9);
        const v2f* fr1 = fr0 + (1L << 18);
        v2f A0 = fr0[tid + 256], B0 = fr0[tid];
        v2f A1 = fr1[tid + 256], B1 = fr1[tid];
        A0 *= ia; B0 *= ib; A1 *= ia; B1 *= ib;

        // stage q=256 twiddles synthesized: w = e^{-2pi i tid/1024}
        float sw0, cw0;
        __sincosf((-2.0f * PI_F / 1024.0f) * (float)tid, &sw0, &cw0);
        v2f wt = {cw0, sw0};
        float4 t1p = tw4p(wt);
        float4 t2p = tw4p(cmulv(wt, wt));
        float4 t3p = tw4p(cmulv(cmulv(wt, wt), wt));

        #pragma unroll
        for (int b = 0; b < 2; ++b) {
            v2f A = b ? A1 : A0, B = b ? B1 : B0;
            __syncthreads();                     // T ready / WAR on s
            v2f rB = irot(B);
            s[PIDX(tid)]       = A + B;
            s[PIDX(tid + 256)] = cmul4(A + rB, t1p);
            s[PIDX(tid + 512)] = cmul4(A - B,  t2p);
            s[PIDX(tid + 768)] = cmul4(A - rB, t3p);

            int off = 0, q = 64;                 // stages q=64,16,4,1 in LDS
            #pragma unroll
            for (int st = 0; st < 4; ++st) {
                __syncthreads();
                bfly4(s, T, tid, q, off);
                off += 3 * q; q >>= 2;
            }
            __syncthreads();

            v2f* base = g + ((long)b << 20) + ((long)row << 10);
            #pragma unroll
            for (int i = 0; i < 4; ++i) {
                int idx = tid + (i << 8);
                base[idx] = s[PIDX(digitrev4_10(idx))];
            }
        }
    } else {
        // ---- binning: 4096 points per block, split records ----
        int* h = (int*)smem;                     // 2048 ints
        int bblk = blockIdx.x - 512;             // 0..255
        for (int i = tid; i < BINS; i += 256) h[i] = 0;
        __syncthreads();

        int base = bblk * 4096;
        int tile[16];
        v2f pv[16];
        #pragma unroll
        for (int i = 0; i < 16; ++i) {
            int gid = base + tid + i * 256;
            pv[i]   = x[gid];
            tile[i] = tile_of(pv[i], gid >> 19);
            atomicAdd(&h[tile[i]], 1);
        }
        __syncthreads();

        #pragma unroll
        for (int j = 0; j < 8; ++j) {
            int bi = tid + j * 256;
            int c  = h[bi];
            h[bi]  = c ? atomicAdd(&gcnt[bi], c) : 0;
        }
        __syncthreads();

        #pragma unroll
        for (int i = 0; i < 16; ++i) {
            int gid  = base + tid + i * 256;
            int pos  = atomicAdd(&h[tile[i]], 1);
            int slot = tile[i] * CAP + pos;
            pxy[slot] = pv[i];
            pid[slot] = gid;
        }
    }
}

// Column FFTs (radix-4), 4 columns per block, 64 threads per FFT.
// Stages q=256,64 in registers with synthesized twiddles; q=16 in LDS;
// q=4,1 in registers on a contiguous padded chunk; direct digit-reversed
// global write.
__global__ __launch_bounds__(256) void fft_cols(v2f* __restrict__ g) {
    constexpr int STR = 1092;                  // >= PIDX(1023)+1, mod 16 = 4
    __shared__ v2f    s[4 * STR];              // 34944 B
    __shared__ float4 Tsm[60];                 // q=16 @0 (48), q=4 @48 (12)
    int b  = blockIdx.y;
    int C0 = blockIdx.x * 4;
    int t  = threadIdx.x;
    int c  = t & 3, L = t >> 2;                // L in 0..63
    v2f* gb = g + ((long)b << 20);

    build_tw_small(Tsm, t, 256, 16, 16, 2);

    v2f E[16];
    #pragma unroll
    for (int m = 0; m < 4; ++m) {              // rows 0..255
        int r = L + 64 * m;
        E[m] = gb[((long)r << 10) + C0 + c];
    }
    #pragma unroll
    for (int m = 12; m < 16; ++m) {            // rows 768..1023
        int r = L + 64 * m;
        E[m] = gb[((long)r << 10) + C0 + c];
    }

    // wL = e^{-2pi i L/1024}; R[m] = e^{-i pi m/8} rotation constants
    float sL, cL;
    __sincosf((-2.0f * PI_F / 1024.0f) * (float)L, &sL, &cL);
    v2f wL = {cL, sL};
    const v2f R1 = {0.923879533f, -0.382683432f};
    const v2f R2 = {0.707106781f, -0.707106781f};
    const v2f R3 = {0.382683432f, -0.923879533f};

    // stage q=256 in registers: groups {m, m+4, m+8, m+12} = {A,0,0,B},
    // twiddle base w1 = e^{-2pi i (L+64m)/1024} = wL * R[m]
    #pragma unroll
    for (int m = 0; m < 4; ++m) {
        v2f w1 = (m == 0) ? wL : cmulv(wL, (m == 1) ? R1 : (m == 2) ? R2 : R3);
        v2f w2 = cmulv(w1, w1);
        v2f w3 = cmulv(w2, w1);
        v2f A = E[m], B = E[m + 12];
        v2f rB = irot(B);
        E[m]      = A + B;
        E[m + 4]  = cmul4(A + rB, tw4p(w1));
        E[m + 8]  = cmul4(A - B,  tw4p(w2));
        E[m + 12] = cmul4(A - rB, tw4p(w3));
    }

    // stage q=64 in registers: groups {4a+0..3}, twiddle base u = wL^4
    {
        v2f p  = cmulv(wL, wL); p = cmulv(p, p);     // wL^4
        v2f p2 = cmulv(p, p);
        v2f p3 = cmulv(p2, p);
        float4 u1 = tw4p(p), u2 = tw4p(p2), u3 = tw4p(p3);
        #pragma unroll
        for (int a = 0; a < 4; ++a) {
            v2f a0 = E[4*a], a1 = E[4*a+1], a2 = E[4*a+2], a3 = E[4*a+3];
            v2f t0 = a0 + a2, t1 = a0 - a2, t2 = a1 + a3, t3 = a1 - a3;
            v2f r3 = irot(t3);
            E[4*a]   = t0 + t2;
            E[4*a+1] = cmul4(t1 - r3, u1);
            E[4*a+2] = cmul4(t0 - t2, u2);
            E[4*a+3] = cmul4(t1 + r3, u3);
        }
    }

    __syncthreads();                           // Tsm ready
    v2f* sf = s + c * STR;
    #pragma unroll
    for (int m = 0; m < 16; ++m) sf[PIDX(L + 64 * m)] = E[m];
    __syncthreads();

    // stage q=16 in LDS (table offset 0)
    #pragma unroll
    for (int rr = 0; rr < 4; ++rr)
        bfly4(sf, Tsm, L + rr * 64, 16, 0);
    __syncthreads();

    // contiguous chunk read (lane stride 17 v2f -> 2-way, free)
    v2f C[16];
    int cb = 17 * L;                           // PIDX(16L)
    #pragma unroll
    for (int j = 0; j < 16; ++j) C[j] = sf[cb + j];

    // stage q=4 in registers (table offset 48)
    #pragma unroll
    for (int j = 0; j < 4; ++j) {
        v2f a0 = C[j], a1 = C[j+4], a2 = C[j+8], a3 = C[j+12];
        v2f t0 = a0 + a2, t1 = a0 - a2, t2 = a1 + a3, t3 = a1 - a3;
        v2f r3 = irot(t3);
        C[j]    = t0 + t2;
        C[j+4]  = cmul4(t1 - r3, Tsm[48 + j]);
        C[j+8]  = cmul4(t0 - t2, Tsm[52 + j]);
        C[j+12] = cmul4(t1 + r3, Tsm[56 + j]);
    }
    // stage q=1 in registers (twiddles identically 1)
    #pragma unroll
    for (int e = 0; e < 4; ++e) {
        v2f a0 = C[4*e], a1 = C[4*e+1], a2 = C[4*e+2], a3 = C[4*e+3];
        v2f t0 = a0 + a2, t1 = a0 - a2, t2 = a1 + a3, t3 = a1 - a3;
        v2f r3 = irot(t3);
        C[4*e]   = t0 + t2;
        C[4*e+1] = t1 - r3;
        C[4*e+2] = t0 - t2;
        C[4*e+3] = t1 + r3;
    }

    // direct digit-reversed write: element f=16L+j -> row digitrev(f)
    #pragma unroll
    for (int j = 0; j < 16; ++j) {
        int r = digitrev4_10((L << 4) + j);
        gb[((long)r << 10) + C0 + c] = C[j];
    }
}

// ---------------- binned gather, 6 taps/dim ----------------
// Weights via transcendentals (LDS tables regressed in round 9). Points
// from split perm streams (contiguous). Patch 37x37 v2f, stride 37 (odd).
__global__ __launch_bounds__(256) void gather_binned(const v2f* __restrict__ g,
                                                     const int* __restrict__ gcnt,
                                                     const v2f* __restrict__ pxy,
                                                     const int* __restrict__ pid,
                                                     v2f* __restrict__ out) {
    __shared__ v2f patch[37 * 37];             // 10.9 KB
    int tb = blockIdx.x;           // 0..2047
    int b  = tb >> 10;
    int tt = tb & 1023;
    int tR = tt >> 5, tC = tt & 31;
    int R0 = (tR << 5) - 2, C0 = (tC << 5) - 2;
    const v2f* gb = g + ((long)b << 20);

    for (int p = threadIdx.x; p < 37 * 37; p += 256) {
        int pr = p / 37, pc = p - pr * 37;
        int gr = (R0 + pr) & 1023, gc = (C0 + pc) & 1023;
        patch[p] = gb[(gr << 10) + gc];
    }
    __syncthreads();

    int cnt = gcnt[tb];
    if (cnt > CAP) cnt = CAP;
    int off0 = tb * CAP;
    for (int i = (int)threadIdx.x; i < cnt; i += 256) {
        v2f xv  = pxy[off0 + i];
        int gid = pid[off0 + i];

        float w1[6], w2[6];
        int rr0, cc0;
        {
            float xs = xv.x * 1024.0f;
            float fl = floorf(xs);
            float fr = xs - fl;
            rr0 = (((int)fl) & 1023) - (tR << 5);     // 0..31
            #pragma unroll
            for (int k = 0; k < 6; ++k) {
                float tv = fr - (float)(k - 2);       // |tv| < 3 -> u2 > 7
                float u2 = 16.0f - tv * tv;
                float ir = rsqrtf(u2);                // 1/u
                float z  = BETA * u2 * ir;            // beta*u in [12.5,18.9]
                w1[k] = __expf(z) * 0.159154943f * ir;   // sinh(z)/(pi*u)
            }
        }
        {
            float xs = xv.y * 1024.0f;
            float fl = floorf(xs);
            float fr = xs - fl;
            cc0 = (((int)fl) & 1023) - (tC << 5);     // 0..31
            #pragma unroll
            for (int k = 0; k < 6; ++k) {
                float tv = fr - (float)(k - 2);
                float u2 = 16.0f - tv * tv;
                float ir = rsqrtf(u2);
                float z  = BETA * u2 * ir;
                w2[k] = __expf(z) * 0.159154943f * ir;
            }
        }

        v2f acc = {0.0f, 0.0f};
        #pragma unroll
        for (int ii = 0; ii < 6; ++ii) {
            int pbase = (rr0 + ii) * 37 + cc0;
            float wi = w1[ii];
            #pragma unroll
            for (int jj = 0; jj < 6; ++jj)
                acc += (wi * w2[jj]) * patch[pbase + jj];   // v_pk_fma_f32
        }
        out[gid] = acc;
    }
}

extern "C" void kernel_launch(void* const* d_in, const int* in_sizes, int n_in,
                              void* d_out, int out_size, void* d_ws, size_t ws_size,
                              hipStream_t stream) {
    const v2f* x  = (const v2f*)d_in[0];
    const v2f* fh = (const v2f*)d_in[1];
    char* ws = (char*)d_ws;
    v2f* g    = (v2f*)ws;
    int* gcnt = (int*)(ws + GCNT_OFF);
    v2f* pxy  = (v2f*)(ws + PXY_OFF);
    int* pid  = (int*)(ws + PID_OFF);

    rows_and_bin<<<dim3(768), dim3(256), 0, stream>>>(fh, g, x, gcnt, pxy, pid);
    fft_cols    <<<dim3(256, BATCH), dim3(256), 0, stream>>>(g);

    gather_binned<<<dim3(BINS), dim3(256), 0, stream>>>(g, gcnt, pxy, pid,
                                                        (v2f*)d_out);
}

// Round 16
// 114.969 us; speedup vs baseline: 1.1019x; 1.1019x over previous
//
#include <hip/hip_runtime.h>

constexpr int   BATCH = 2;
constexpr int   NPTS  = 524288;            // P = 2^19
constexpr int   BINS  = 2048;              // BATCH * 32 * 32 tiles
constexpr int   CAP   = 768;               // per-bin capacity (mean 512, +11 sigma)
constexpr float BETA  = 4.71238898038469f; // 1.5*pi
constexpr float PI_F  = 3.14159265358979f;

typedef float v2f __attribute__((ext_vector_type(2)));

// LDS pad-16: breaks power-of-2 strides (butterflies + digit-rev readout)
#define PIDX(i) ((i) + ((i) >> 4))

// ---------------- workspace layout ----------------
// g    : 16 MB @ 0
// gcnt : 8 KB  @ 16 MB          (zeroed by block 0 of rows_and_bin)
// perm : BINS x CAP float4 records {x.x, x.y, gid, -} = 25.2 MB
constexpr size_t G_BYTES  = (size_t)BATCH * 1024 * 1024 * sizeof(v2f);
constexpr size_t GCNT_OFF = G_BYTES;
constexpr size_t PERM_OFF = G_BYTES + 8192;

// i0(x) for x >= 3.75 (Numerical Recipes asymptotic, rel err ~1e-7)
__device__ __forceinline__ float i0f_large(float x) {
    float t = 3.75f / x;
    float p =  0.00392377f;
    p = p * t + -0.01647633f;
    p = p * t +  0.02635537f;
    p = p * t + -0.02057706f;
    p = p * t +  0.00916281f;
    p = p * t + -0.00157565f;
    p = p * t +  0.00225319f;
    p = p * t +  0.01328592f;
    p = p * t +  0.39894228f;
    return __expf(x) * rsqrtf(x) * p;
}

__device__ __forceinline__ int tile_of(v2f xv, int b) {
    int c1 = ((int)floorf(xv.x * 1024.0f)) & 1023;
    int c2 = ((int)floorf(xv.y * 1024.0f)) & 1023;
    return (b << 10) + ((c1 >> 5) << 5) + (c2 >> 5);
}

// cmul via packed f32: t stores (c, s, -s, c); a*w = a.x*(c,s) + a.y*(-s,c)
__device__ __forceinline__ v2f cmul4(v2f a, float4 t) {
    v2f lo = {t.x, t.y}, hi = {t.z, t.w};
    return a.x * lo + a.y * hi;            // v_pk_mul + v_pk_fma
}
__device__ __forceinline__ v2f irot(v2f b) { return (v2f){-b.y, b.x}; }  // i*b

// Natural freq f -> storage position after radix-4 DIF (5 digit-reversed
// base-4 digits) = bit-reverse then swap bits within pairs. Involution.
__device__ __forceinline__ int digitrev4_10(int f) {
    unsigned r = __brev((unsigned)f) >> 22;
    return (int)(((r & 0x2AAu) >> 1) | ((r & 0x155u) << 1));
}

// Stage-concatenated radix-4 twiddles, 1023 float4 (c,s,-s,c):
// stage offsets: q=256 @0, q=64 @768, q=16 @960, q=4 @1008, q=1 @1020.
__device__ __forceinline__ void build_tw4(float4* T, int tid, int nthreads) {
    int off = 0, q = 256, sig = 1;
    #pragma unroll
    for (int st = 0; st < 5; ++st) {
        for (int m = tid; m < 3 * q; m += nthreads) {
            int sec = 0, j = m;
            if (j >= q) { sec++; j -= q; }
            if (j >= q) { sec++; j -= q; }
            float ang = (-2.0f * PI_F / 1024.0f) * (float)((sec + 1) * j * sig);
            float sw, cw;
            __sincosf(ang, &sw, &cw);
            T[off + m] = make_float4(cw, sw, -sw, cw);
        }
        off += 3 * q; q >>= 2; sig <<= 2;
    }
}

// One radix-4 DIF butterfly at index bt for stage with quarter-stride q.
__device__ __forceinline__ void bfly4(v2f* s, const float4* T,
                                      int bt, int q, int off) {
    int j    = bt & (q - 1);
    int base = ((bt - j) << 2) + j;        // (bt/q)*4q + j
    int p0 = PIDX(base), p1 = PIDX(base + q);
    int p2 = PIDX(base + 2 * q), p3 = PIDX(base + 3 * q);
    v2f a0 = s[p0], a1 = s[p1], a2 = s[p2], a3 = s[p3];
    v2f t0 = a0 + a2, t1 = a0 - a2, t2 = a1 + a3, t3 = a1 - a3;
    v2f r3 = irot(t3);
    s[p0] = t0 + t2;
    s[p1] = cmul4(t1 - r3, T[off + j]);
    s[p2] = cmul4(t0 - t2, T[off + q + j]);
    s[p3] = cmul4(t1 + r3, T[off + 2 * q + j]);
}

// ---------------- fused: row FFTs (blocks 0..1023) + binning (1024..1279) ----
// Block 0 additionally zeroes gcnt via device-scope atomics at t~0 (bin
// blocks do >=2us of loads+LDS histogram before touching gcnt).
__global__ __launch_bounds__(256) void rows_and_bin(const v2f* __restrict__ fh,
                                                    v2f* __restrict__ g,
                                                    const v2f* __restrict__ x,
                                                    int* __restrict__ gcnt,
                                                    float4* __restrict__ perm) {
    // fft path: s = 1088 v2f (8704 B, 16-aligned), T = 1023 float4 (16368 B)
    __shared__ __align__(16) char smem[25072];
    int tid = threadIdx.x;

    if (blockIdx.x < 1024) {
        if (blockIdx.x == 0) {
            #pragma unroll
            for (int i = 0; i < 8; ++i)
                atomicExch(&gcnt[tid * 8 + i], 0);
        }
        // ---- row FFT fused with deconvolution (radix-4) ----
        v2f*    s = (v2f*)smem;                  // 1087 used
        float4* T = (float4*)(smem + 8704);      // 1023
        int blk = blockIdx.x & 511;              // 0..511
        int b   = blockIdx.x >> 9;
        int row = (blk < 256) ? blk : blk + 512; // {0..255, 768..1023}
        int a1  = (row + 256) & 1023;            // fh row index, 0..511

        build_tw4(T, tid, 256);

        float k1 = (float)(a1 - 256);
        float w1 = (2.0f * PI_F / 1024.0f) * k1;
        float c1 = i0f_large(4.0f * sqrtf(BETA * BETA - w1 * w1));

        const v2f* fr = fh + ((long)b << 18) + ((long)a1 << 9);

        float w2a = (2.0f * PI_F / 1024.0f) * (float)tid;
        float c2a = i0f_large(4.0f * sqrtf(BETA * BETA - w2a * w2a));
        float w2b = (2.0f * PI_F / 1024.0f) * (float)(tid - 256);
        float c2b = i0f_large(4.0f * sqrtf(BETA * BETA - w2b * w2b));

        v2f A = fr[tid + 256] * (1.0f / (c1 * c2a));   // idx tid
        v2f B = fr[tid]       * (1.0f / (c1 * c2b));   // idx tid+768

        __syncthreads();                          // T ready

        // stage q=256 in regs: {A,0,0,B} -> A+B, (A+iB)w1, (A-B)w2, (A-iB)w3
        v2f rB = irot(B);
        s[PIDX(tid)]       = A + B;
        s[PIDX(tid + 256)] = cmul4(A + rB, T[tid]);
        s[PIDX(tid + 512)] = cmul4(A - B,  T[256 + tid]);
        s[PIDX(tid + 768)] = cmul4(A - rB, T[512 + tid]);

        int off = 768, q = 64;                    // stages q=64,16,4,1 in LDS
        #pragma unroll
        for (int st = 0; st < 4; ++st) {
            __syncthreads();
            bfly4(s, T, tid, q, off);
            off += 3 * q; q >>= 2;
        }
        __syncthreads();

        v2f* base = g + ((long)b << 20) + ((long)row << 10);
        #pragma unroll
        for (int i = 0; i < 4; ++i) {
            int idx = tid + (i << 8);
            base[idx] = s[PIDX(digitrev4_10(idx))];
        }
    } else {
        // ---- binning: 4096 points per block, fat records {x, gid} ----
        int* h = (int*)smem;                     // 2048 ints
        int bblk = blockIdx.x - 1024;            // 0..255
        for (int i = tid; i < BINS; i += 256) h[i] = 0;
        __syncthreads();

        int base = bblk * 4096;
        int tile[16];
        v2f pv[16];
        #pragma unroll
        for (int i = 0; i < 16; ++i) {
            int gid = base + tid + i * 256;
            pv[i]   = x[gid];
            tile[i] = tile_of(pv[i], gid >> 19);
            atomicAdd(&h[tile[i]], 1);
        }
        __syncthreads();

        #pragma unroll
        for (int j = 0; j < 8; ++j) {
            int bi = tid + j * 256;
            int c  = h[bi];
            h[bi]  = c ? atomicAdd(&gcnt[bi], c) : 0;
        }
        __syncthreads();

        #pragma unroll
        for (int i = 0; i < 16; ++i) {
            int gid = base + tid + i * 256;
            int pos = atomicAdd(&h[tile[i]], 1);
            perm[tile[i] * CAP + pos] =
                make_float4(pv[i].x, pv[i].y, __int_as_float(gid), 0.0f);
        }
    }
}

// Column FFTs (radix-4), 4 columns per block, 64 threads per FFT.
// Stages q=256,64 in registers; q=16 in LDS; q=4,1 in registers on a
// CONTIGUOUS padded chunk (PIDX(16L+j) = 17L+j), then direct digit-reversed
// global write (same 32B-segment coalescing as an LDS readout).
__global__ __launch_bounds__(256) void fft_cols(v2f* __restrict__ g) {
    constexpr int STR = 1092;                  // >= PIDX(1023)+1, mod 16 = 4
    __shared__ v2f    s[4 * STR];              // ~35 KB
    __shared__ float4 T[1023];                 // 16 KB
    int b  = blockIdx.y;
    int C0 = blockIdx.x * 4;
    int t  = threadIdx.x;
    int c  = t & 3, L = t >> 2;                // L in 0..63
    v2f* gb = g + ((long)b << 20);

    build_tw4(T, t, 256);

    v2f E[16];
    #pragma unroll
    for (int m = 0; m < 4; ++m) {              // rows 0..255
        int r = L + 64 * m;
        E[m] = gb[((long)r << 10) + C0 + c];
    }
    #pragma unroll
    for (int m = 12; m < 16; ++m) {            // rows 768..1023
        int r = L + 64 * m;
        E[m] = gb[((long)r << 10) + C0 + c];
    }
    __syncthreads();                           // T ready

    // stage q=256 in registers: groups {m, m+4, m+8, m+12} = {A,0,0,B}
    #pragma unroll
    for (int m = 0; m < 4; ++m) {
        v2f A = E[m], B = E[m + 12];
        v2f rB = irot(B);
        int j = L + 64 * m;
        E[m]      = A + B;
        E[m + 4]  = cmul4(A + rB, T[j]);
        E[m + 8]  = cmul4(A - B,  T[256 + j]);
        E[m + 12] = cmul4(A - rB, T[512 + j]);
    }

    // stage q=64 in registers: groups {4a+0..3}, j = L for all a
    {
        float4 u1 = T[768 + L], u2 = T[768 + 64 + L], u3 = T[768 + 128 + L];
        #pragma unroll
        for (int a = 0; a < 4; ++a) {
            v2f a0 = E[4*a], a1 = E[4*a+1], a2 = E[4*a+2], a3 = E[4*a+3];
            v2f t0 = a0 + a2, t1 = a0 - a2, t2 = a1 + a3, t3 = a1 - a3;
            v2f r3 = irot(t3);
            E[4*a]   = t0 + t2;
            E[4*a+1] = cmul4(t1 - r3, u1);
            E[4*a+2] = cmul4(t0 - t2, u2);
            E[4*a+3] = cmul4(t1 + r3, u3);
        }
    }

    v2f* sf = s + c * STR;
    #pragma unroll
    for (int m = 0; m < 16; ++m) sf[PIDX(L + 64 * m)] = E[m];
    __syncthreads();

    // stage q=16 in LDS
    #pragma unroll
    for (int rr = 0; rr < 4; ++rr)
        bfly4(sf, T, L + rr * 64, 16, 960);
    __syncthreads();

    // contiguous chunk read (lane stride 17 v2f -> 2-way, free)
    v2f C[16];
    int cb = 17 * L;                           // PIDX(16L)
    #pragma unroll
    for (int j = 0; j < 16; ++j) C[j] = sf[cb + j];

    // stage q=4 in registers (off 1008)
    #pragma unroll
    for (int j = 0; j < 4; ++j) {
        v2f a0 = C[j], a1 = C[j+4], a2 = C[j+8], a3 = C[j+12];
        v2f t0 = a0 + a2, t1 = a0 - a2, t2 = a1 + a3, t3 = a1 - a3;
        v2f r3 = irot(t3);
        C[j]    = t0 + t2;
        C[j+4]  = cmul4(t1 - r3, T[1008 + j]);
        C[j+8]  = cmul4(t0 - t2, T[1012 + j]);
        C[j+12] = cmul4(t1 + r3, T[1016 + j]);
    }
    // stage q=1 in registers (twiddles identically 1)
    #pragma unroll
    for (int e = 0; e < 4; ++e) {
        v2f a0 = C[4*e], a1 = C[4*e+1], a2 = C[4*e+2], a3 = C[4*e+3];
        v2f t0 = a0 + a2, t1 = a0 - a2, t2 = a1 + a3, t3 = a1 - a3;
        v2f r3 = irot(t3);
        C[4*e]   = t0 + t2;
        C[4*e+1] = t1 - r3;
        C[4*e+2] = t0 - t2;
        C[4*e+3] = t1 + r3;
    }

    // direct digit-reversed write: element f=16L+j -> row digitrev(f)
    #pragma unroll
    for (int j = 0; j < 16; ++j) {
        int r = digitrev4_10((L << 4) + j);
        gb[((long)r << 10) + C0 + c] = C[j];
    }
}

// ---------------- binned gather, 6 taps/dim ----------------
// Weights via transcendentals (trans pipe overlaps LDS waits; LDS tables
// regressed in round 9). Points from fat perm records. Patch 37x37 v2f.
__global__ __launch_bounds__(256) void gather_binned(const v2f* __restrict__ g,
                                                     const int* __restrict__ gcnt,
                                                     const float4* __restrict__ perm,
                                                     v2f* __restrict__ out) {
    __shared__ v2f patch[37 * 37];             // 10.9 KB
    int tb = blockIdx.x;           // 0..2047
    int b  = tb >> 10;
    int tt = tb & 1023;
    int tR = tt >> 5, tC = tt & 31;
    int R0 = (tR << 5) - 2, C0 = (tC << 5) - 2;
    const v2f* gb = g + ((long)b << 20);

    for (int p = threadIdx.x; p < 37 * 37; p += 256) {
        int pr = p / 37, pc = p - pr * 37;
        int gr = (R0 + pr) & 1023, gc = (C0 + pc) & 1023;
        patch[p] = gb[(gr << 10) + gc];
    }
    __syncthreads();

    int cnt = gcnt[tb];
    if (cnt > CAP) cnt = CAP;
    int off0 = tb * CAP;
    for (int i = (int)threadIdx.x; i < cnt; i += 256) {
        float4 rec = perm[off0 + i];
        int gid = __float_as_int(rec.z);

        float w1[6], w2[6];
        int rr0, cc0;
        {
            float xs = rec.x * 1024.0f;
            float fl = floorf(xs);
            float fr = xs - fl;
            rr0 = (((int)fl) & 1023) - (tR << 5);     // 0..31
            #pragma unroll
            for (int k = 0; k < 6; ++k) {
                float tv = fr - (float)(k - 2);       // |tv| < 3 -> u2 > 7
                float u2 = 16.0f - tv * tv;
                float ir = rsqrtf(u2);                // 1/u
                float z  = BETA * u2 * ir;            // beta*u in [12.5,18.9]
                w1[k] = __expf(z) * 0.159154943f * ir;   // sinh(z)/(pi*u)
            }
        }
        {
            float xs = rec.y * 1024.0f;
            float fl = floorf(xs);
            float fr = xs - fl;
            cc0 = (((int)fl) & 1023) - (tC << 5);     // 0..31
            #pragma unroll
            for (int k = 0; k < 6; ++k) {
                float tv = fr - (float)(k - 2);
                float u2 = 16.0f - tv * tv;
                float ir = rsqrtf(u2);
                float z  = BETA * u2 * ir;
                w2[k] = __expf(z) * 0.159154943f * ir;
            }
        }

        v2f acc = {0.0f, 0.0f};
        #pragma unroll
        for (int ii = 0; ii < 6; ++ii) {
            int pbase = (rr0 + ii) * 37 + cc0;
            float wi = w1[ii];
            #pragma unroll
            for (int jj = 0; jj < 6; ++jj)
                acc += (wi * w2[jj]) * patch[pbase + jj];   // v_pk_fma_f32
        }
        out[gid] = acc;
    }
}

extern "C" void kernel_launch(void* const* d_in, const int* in_sizes, int n_in,
                              void* d_out, int out_size, void* d_ws, size_t ws_size,
                              hipStream_t stream) {
    const v2f* x  = (const v2f*)d_in[0];
    const v2f* fh = (const v2f*)d_in[1];
    char* ws = (char*)d_ws;
    v2f*    g    = (v2f*)ws;
    int*    gcnt = (int*)(ws + GCNT_OFF);
    float4* perm = (float4*)(ws + PERM_OFF);

    rows_and_bin<<<dim3(1280), dim3(256), 0, stream>>>(fh, g, x, gcnt, perm);
    fft_cols    <<<dim3(256, BATCH), dim3(256), 0, stream>>>(g);

    gather_binned<<<dim3(BINS), dim3(256), 0, stream>>>(g, gcnt, perm, (v2f*)d_out);
}